// Round 2
// baseline (290.653 us; speedup 1.0000x reference)
//
#include <hip/hip_runtime.h>

// Multi-head causal attention fwd, B=2 S=2048 D=1024 H=16 DK=DV=64.
// fp32 I/O; internal bf16 MFMA pipeline.
// 6 dispatches: convert(fp32->bf16) gemm(Q) gemm(K) gemm(Vt) flash-attn gemm(out).

typedef __bf16 bf16;
typedef __bf16 bf16x8 __attribute__((ext_vector_type(8)));
typedef __bf16 bf16x4 __attribute__((ext_vector_type(4)));
typedef float  f32x4  __attribute__((ext_vector_type(4)));

#define B_  2
#define S_  2048
#define D_  1024
#define H_  16
#define HD  64
#define NEG_BIG (-3.0e38f)

__device__ __forceinline__ void lds16(const void* g, void* l) {
    __builtin_amdgcn_global_load_lds((const __attribute__((address_space(1))) void*)g,
                                     (__attribute__((address_space(3))) void*)l, 16, 0, 0);
}

__device__ __forceinline__ f32x4 mfma16(bf16x8 a, bf16x8 b, f32x4 c) {
    return __builtin_amdgcn_mfma_f32_16x16x32_bf16(a, b, c, 0, 0, 0);
}

// ---------------- fp32 -> bf16 convert pre-pass ----------------
// segments (element offsets): X[0,4M) wq[4M,5M) wk[5M,6M) wv[6M,7M) wo[7M,8M)
__global__ __launch_bounds__(256) void convert_k(const float* __restrict__ X,
                                                 const float* __restrict__ wq,
                                                 const float* __restrict__ wk,
                                                 const float* __restrict__ wv,
                                                 const float* __restrict__ wo,
                                                 bf16* __restrict__ dst) {
    const int gid = blockIdx.x * 256 + threadIdx.x;
    const int i   = gid * 4;                     // element index, [0, 8M)
    const float* src;
    int off;
    if      (i < (4 << 20)) { src = X;  off = 0; }
    else if (i < (5 << 20)) { src = wq; off = 4 << 20; }
    else if (i < (6 << 20)) { src = wk; off = 5 << 20; }
    else if (i < (7 << 20)) { src = wv; off = 6 << 20; }
    else                    { src = wo; off = 7 << 20; }
    const float4 v = *(const float4*)(src + (i - off));
    bf16x4 p;
    p[0] = (bf16)v.x; p[1] = (bf16)v.y; p[2] = (bf16)v.z; p[3] = (bf16)v.w;
    *(bf16x4*)(dst + i) = p;
}

// ---------------- GEMM: C[M,N] = A[M,K] @ W[N,K]^T + bias ----------------
// M=4096 N=1024 K=1024, A/W bf16, bias fp32.
// MODE 0: C row-major [M,N] fp32 (final proj -> d_out)
// MODE 1: C scattered to [B,H,S,64] bf16   (Q, K)
// MODE 2: C scattered to [B,H,64,S] bf16   (V transposed for PV contiguity)
template <int MODE, typename CT>
__global__ __launch_bounds__(256) void gemm_bt(const bf16* __restrict__ A,
                                               const bf16* __restrict__ W,
                                               const float* __restrict__ bias,
                                               CT* __restrict__ C) {
    constexpr int N = 1024, K = 1024;
    __shared__ bf16 sA[128 * 32];
    __shared__ bf16 sB[128 * 32];
    const int tid  = threadIdx.x;
    const int l15  = tid & 15;
    const int quad = (tid & 63) >> 4;
    const int wid  = tid >> 6;
    const int bm   = blockIdx.x >> 3;   // 32 row tiles
    const int bn   = blockIdx.x & 7;    // 8 col tiles
    const int wm   = (wid >> 1) * 64;
    const int wn   = (wid & 1) * 64;

    const bf16* Ab = A + (size_t)bm * 128 * K;
    const bf16* Wb = W + (size_t)bn * 128 * K;

    f32x4 acc[4][4] = {};

    for (int k0 = 0; k0 < K; k0 += 32) {
        __syncthreads();                       // prev-iter frag reads done
        #pragma unroll
        for (int it = 0; it < 2; ++it) {       // 512 chunks of 16B per tile
            int c = it * 256 + tid;
            int row = c >> 2, c8 = c & 3;
            lds16(Ab + row * K + k0 + c8 * 8, (char*)sA + c * 16);
            lds16(Wb + row * K + k0 + c8 * 8, (char*)sB + c * 16);
        }
        __syncthreads();                       // drains vmcnt (global_load_lds)
        bf16x8 af[4], bfr[4];
        #pragma unroll
        for (int i = 0; i < 4; ++i)
            af[i] = *(const bf16x8*)&sA[(wm + i * 16 + l15) * 32 + quad * 8];
        #pragma unroll
        for (int i = 0; i < 4; ++i)
            bfr[i] = *(const bf16x8*)&sB[(wn + i * 16 + l15) * 32 + quad * 8];
        #pragma unroll
        for (int mi = 0; mi < 4; ++mi)
            #pragma unroll
            for (int ni = 0; ni < 4; ++ni)
                acc[mi][ni] = mfma16(af[mi], bfr[ni], acc[mi][ni]);
    }

    #pragma unroll
    for (int ni = 0; ni < 4; ++ni) {
        const int n  = bn * 128 + wn + ni * 16 + l15;
        const float bv = bias[n];
        #pragma unroll
        for (int mi = 0; mi < 4; ++mi) {
            const int m0 = bm * 128 + wm + mi * 16 + quad * 4;  // rows m0..m0+3
            if constexpr (MODE == 2) {
                const int h = n >> 6, dv = n & 63;
                const int b = m0 >> 11, s = m0 & 2047;
                bf16x4 pack;
                #pragma unroll
                for (int r = 0; r < 4; ++r) pack[r] = (bf16)(acc[mi][ni][r] + bv);
                *(bf16x4*)&C[(((size_t)(b * H_ + h) * HD + dv) << 11) + s] = pack;
            } else if constexpr (MODE == 1) {
                const int h = n >> 6, dk = n & 63;
                #pragma unroll
                for (int r = 0; r < 4; ++r) {
                    const int m = m0 + r, b = m >> 11, s = m & 2047;
                    C[(((size_t)(b * H_ + h) << 11) + s) * HD + dk] =
                        (CT)(acc[mi][ni][r] + bv);
                }
            } else {
                #pragma unroll
                for (int r = 0; r < 4; ++r)
                    C[(size_t)(m0 + r) * N + n] = (CT)(acc[mi][ni][r] + bv);
            }
        }
    }
}

// ---------------- Flash attention ----------------
// block = (b, h, 128-row q tile), 4 waves, online softmax.
// LDS tiles as [plane][rows][32] so frag reads are 64B-stride ds_read_b128.
__global__ __launch_bounds__(256) void attn_k(const bf16* __restrict__ Q,
                                              const bf16* __restrict__ K,
                                              const bf16* __restrict__ Vt,
                                              const float* __restrict__ pmask,
                                              bf16* __restrict__ Aout) {
    __shared__ bf16 sQ[2 * 128 * 32];   // [kk][qrow][32]
    __shared__ bf16 sK[2 * 128 * 32];   // [kk][krow][32]
    __shared__ bf16 sV[4 * 64 * 32];    // [kc][dv][32]  (V^T: contiguous in key)
    __shared__ bf16 sP[4 * 128 * 32];   // [kc][qrow][32]
    const int tid  = threadIdx.x;
    const int l15  = tid & 15;
    const int quad = (tid & 63) >> 4;
    const int wid  = tid >> 6;
    const int qt   = blockIdx.x & 15;
    const int bh   = blockIdx.x >> 4;
    const int b    = bh >> 4;

    const bf16* Qg = Q + ((size_t)bh * S_ + qt * 128) * HD;
    #pragma unroll
    for (int it = 0; it < 4; ++it) {
        int c = it * 256 + tid;
        int pl = c >> 9, row = (c >> 2) & 127, c8 = c & 3;
        lds16(Qg + row * HD + pl * 32 + c8 * 8, (char*)sQ + c * 16);
    }
    __syncthreads();
    bf16x8 aq[2][2];
    #pragma unroll
    for (int ti = 0; ti < 2; ++ti)
        #pragma unroll
        for (int kk = 0; kk < 2; ++kk)
            aq[ti][kk] = *(const bf16x8*)
                &sQ[(kk * 128 + wid * 32 + ti * 16 + l15) * 32 + quad * 8];

    float m_i[2][4], l_i[2][4];
    f32x4 o[2][4] = {};
    #pragma unroll
    for (int ti = 0; ti < 2; ++ti)
        #pragma unroll
        for (int r = 0; r < 4; ++r) { m_i[ti][r] = NEG_BIG; l_i[ti][r] = 0.f; }

    for (int kt = 0; kt <= qt; ++kt) {
        __syncthreads();                      // all waves done with sK/sV
        const bf16* Kg = K  + ((size_t)bh * S_ + kt * 128) * HD;
        const bf16* Vg = Vt + (size_t)bh * HD * S_ + kt * 128;
        #pragma unroll
        for (int it = 0; it < 4; ++it) {
            int c = it * 256 + tid;
            { int pl = c >> 9, row = (c >> 2) & 127, c8 = c & 3;
              lds16(Kg + row * HD + pl * 32 + c8 * 8, (char*)sK + c * 16); }
            { int kc = c >> 8, dv = (c >> 2) & 63, c8 = c & 3;
              lds16(Vg + dv * S_ + kc * 32 + c8 * 8, (char*)sV + c * 16); }
        }
        __syncthreads();

        // S = Q K^T  (each wave: 32 q rows x 128 keys)
        f32x4 s[2][8] = {};
        #pragma unroll
        for (int tc = 0; tc < 8; ++tc) {
            #pragma unroll
            for (int kk = 0; kk < 2; ++kk) {
                bf16x8 bk = *(const bf16x8*)
                    &sK[(kk * 128 + tc * 16 + l15) * 32 + quad * 8];
                s[0][tc] = mfma16(aq[0][kk], bk, s[0][tc]);
                s[1][tc] = mfma16(aq[1][kk], bk, s[1][tc]);
            }
        }

        // scale + padding + causal mask
        float pmadd[8];
        #pragma unroll
        for (int tc = 0; tc < 8; ++tc) {
            int kg = kt * 128 + tc * 16 + l15;
            pmadd[tc] = (pmask[b * S_ + kg] > 0.f) ? NEG_BIG : 0.f;
        }
        const bool diag = (kt == qt);
        #pragma unroll
        for (int ti = 0; ti < 2; ++ti)
            #pragma unroll
            for (int tc = 0; tc < 8; ++tc)
                #pragma unroll
                for (int r = 0; r < 4; ++r) {
                    float v = s[ti][tc][r] * 0.125f + pmadd[tc];
                    if (diag) {
                        int kl = tc * 16 + l15;
                        int ql = wid * 32 + ti * 16 + quad * 4 + r;
                        if (kl > ql) v = NEG_BIG;
                    }
                    s[ti][tc][r] = v;
                }

        // online softmax (rows replicated across the 16 lanes of a quad)
        #pragma unroll
        for (int ti = 0; ti < 2; ++ti)
            #pragma unroll
            for (int r = 0; r < 4; ++r) {
                float rm = s[ti][0][r];
                #pragma unroll
                for (int tc = 1; tc < 8; ++tc) rm = fmaxf(rm, s[ti][tc][r]);
                rm = fmaxf(rm, __shfl_xor(rm, 1, 16));
                rm = fmaxf(rm, __shfl_xor(rm, 2, 16));
                rm = fmaxf(rm, __shfl_xor(rm, 4, 16));
                rm = fmaxf(rm, __shfl_xor(rm, 8, 16));
                float mn    = fmaxf(m_i[ti][r], rm);
                float alpha = __expf(m_i[ti][r] - mn);
                m_i[ti][r]  = mn;
                float rs = 0.f;
                #pragma unroll
                for (int tc = 0; tc < 8; ++tc) {
                    float p = __expf(s[ti][tc][r] - mn);
                    s[ti][tc][r] = p;
                    rs += p;
                }
                rs += __shfl_xor(rs, 1, 16);
                rs += __shfl_xor(rs, 2, 16);
                rs += __shfl_xor(rs, 4, 16);
                rs += __shfl_xor(rs, 8, 16);
                l_i[ti][r] = l_i[ti][r] * alpha + rs;
                #pragma unroll
                for (int vc = 0; vc < 4; ++vc) o[ti][vc][r] *= alpha;
            }

        // P: C-layout -> LDS (A-layout source for PV)
        #pragma unroll
        for (int ti = 0; ti < 2; ++ti)
            #pragma unroll
            for (int tc = 0; tc < 8; ++tc)
                #pragma unroll
                for (int r = 0; r < 4; ++r) {
                    int ql = wid * 32 + ti * 16 + quad * 4 + r;
                    int kl = tc * 16 + l15;
                    sP[((kl >> 5) * 128 + ql) * 32 + (kl & 31)] =
                        (bf16)s[ti][tc][r];
                }
        __syncthreads();

        // O += P V
        #pragma unroll
        for (int kc = 0; kc < 4; ++kc) {
            bf16x8 ap[2];
            #pragma unroll
            for (int ti = 0; ti < 2; ++ti)
                ap[ti] = *(const bf16x8*)
                    &sP[(kc * 128 + wid * 32 + ti * 16 + l15) * 32 + quad * 8];
            #pragma unroll
            for (int vc = 0; vc < 4; ++vc) {
                bf16x8 bv = *(const bf16x8*)
                    &sV[(kc * 64 + vc * 16 + l15) * 32 + quad * 8];
                o[0][vc] = mfma16(ap[0], bv, o[0][vc]);
                o[1][vc] = mfma16(ap[1], bv, o[1][vc]);
            }
        }
    }

    // epilogue: O/l -> att[B*S, H*64]
    const int h = bh & 15;
    #pragma unroll
    for (int ti = 0; ti < 2; ++ti)
        #pragma unroll
        for (int r = 0; r < 4; ++r) {
            float inv = 1.f / l_i[ti][r];
            int q = qt * 128 + wid * 32 + ti * 16 + quad * 4 + r;
            size_t base = ((size_t)b * S_ + q) * D_ + h * HD;
            #pragma unroll
            for (int vc = 0; vc < 4; ++vc)
                Aout[base + vc * 16 + l15] = (bf16)(o[ti][vc][r] * inv);
        }
}

extern "C" void kernel_launch(void* const* d_in, const int* in_sizes, int n_in,
                              void* d_out, int out_size, void* d_ws, size_t ws_size,
                              hipStream_t stream) {
    const float* X   = (const float*)d_in[0];
    const float* pm  = (const float*)d_in[1];
    const float* wq  = (const float*)d_in[2];
    const float* bq  = (const float*)d_in[3];
    const float* wk  = (const float*)d_in[4];
    const float* bk  = (const float*)d_in[5];
    const float* wv  = (const float*)d_in[6];
    const float* bvb = (const float*)d_in[7];
    const float* wo  = (const float*)d_in[8];
    const float* bo  = (const float*)d_in[9];
    float* out = (float*)d_out;

    char* ws = (char*)d_ws;
    bf16* Xb  = (bf16*)(ws);                  // 4M elems  8 MiB  @ 0
    bf16* Wqb = (bf16*)(ws + (8u  << 20));    // 1M elems  2 MiB
    bf16* Wkb = (bf16*)(ws + (10u << 20));
    bf16* Wvb = (bf16*)(ws + (12u << 20));
    bf16* Wob = (bf16*)(ws + (14u << 20));
    bf16* Qw  = (bf16*)(ws + (16u << 20));    // [B,H,S,64]  8 MiB
    bf16* Kw  = (bf16*)(ws + (24u << 20));    // [B,H,S,64]  8 MiB
    bf16* Vw  = (bf16*)(ws + (32u << 20));    // [B,H,64,S]  8 MiB
    bf16* Aw  = (bf16*)(ws + (40u << 20));    // [B*S, 1024] 8 MiB

    dim3 blk(256);
    convert_k<<<dim3(8192), blk, 0, stream>>>(X, wq, wk, wv, wo, Xb);
    gemm_bt<1, bf16> <<<dim3(256), blk, 0, stream>>>(Xb, Wqb, bq, Qw);
    gemm_bt<1, bf16> <<<dim3(256), blk, 0, stream>>>(Xb, Wkb, bk, Kw);
    gemm_bt<2, bf16> <<<dim3(256), blk, 0, stream>>>(Xb, Wvb, bvb, Vw);
    attn_k<<<dim3(512), blk, 0, stream>>>(Qw, Kw, Vw, pm, Aw);
    gemm_bt<0, float><<<dim3(256), blk, 0, stream>>>(Aw, Wob, bo, out);
}

// Round 3
// 221.823 us; speedup vs baseline: 1.3103x; 1.3103x over previous
//
#include <hip/hip_runtime.h>

// Multi-head causal attention fwd, B=2 S=2048 D=1024 H=16 DK=DV=64.
// fp32 I/O; internal bf16 MFMA pipeline.
// 4 dispatches: convert, fused-QKV gemm, flash-attn, final gemm.

typedef __bf16 bf16;
typedef __bf16 bf16x8 __attribute__((ext_vector_type(8)));
typedef __bf16 bf16x4 __attribute__((ext_vector_type(4)));
typedef float  f32x4  __attribute__((ext_vector_type(4)));

#define B_  2
#define S_  2048
#define D_  1024
#define H_  16
#define HD  64
#define NEG_BIG (-3.0e38f)
#define SCALE_LOG2E 0.1803368801111204f   // (1/8) * log2(e)

__device__ __forceinline__ void lds16(const void* g, void* l) {
    __builtin_amdgcn_global_load_lds((const __attribute__((address_space(1))) void*)g,
                                     (__attribute__((address_space(3))) void*)l, 16, 0, 0);
}

__device__ __forceinline__ f32x4 mfma16(bf16x8 a, bf16x8 b, f32x4 c) {
    return __builtin_amdgcn_mfma_f32_16x16x32_bf16(a, b, c, 0, 0, 0);
}

// ---------------- fp32 -> bf16 convert pre-pass ----------------
__global__ __launch_bounds__(256) void convert_k(const float* __restrict__ X,
                                                 const float* __restrict__ wq,
                                                 const float* __restrict__ wk,
                                                 const float* __restrict__ wv,
                                                 const float* __restrict__ wo,
                                                 bf16* __restrict__ dst) {
    const int gid = blockIdx.x * 256 + threadIdx.x;
    const int i   = gid * 4;
    const float* src;
    int off;
    if      (i < (4 << 20)) { src = X;  off = 0; }
    else if (i < (5 << 20)) { src = wq; off = 4 << 20; }
    else if (i < (6 << 20)) { src = wk; off = 5 << 20; }
    else if (i < (7 << 20)) { src = wv; off = 6 << 20; }
    else                    { src = wo; off = 7 << 20; }
    const float4 v = *(const float4*)(src + (i - off));
    bf16x4 p;
    p[0] = (bf16)v.x; p[1] = (bf16)v.y; p[2] = (bf16)v.z; p[3] = (bf16)v.w;
    *(bf16x4*)(dst + i) = p;
}

// ---------------- fused QKV GEMM ----------------
// grid (24, 32): blockIdx.x = seg*8+bn (seg 0:Q 1:K 2:V), blockIdx.y = bm.
// Q,K -> [B,H,S,64]; V -> [B,H,64,S] (transposed for PV contiguity).
__global__ __launch_bounds__(256) void gemm_qkv(const bf16* __restrict__ A,
                                                const bf16* __restrict__ Wq,
                                                const bf16* __restrict__ Wk,
                                                const bf16* __restrict__ Wv,
                                                const float* __restrict__ bq,
                                                const float* __restrict__ bk,
                                                const float* __restrict__ bv,
                                                bf16* __restrict__ Qw,
                                                bf16* __restrict__ Kw,
                                                bf16* __restrict__ Vw) {
    constexpr int K = 1024;
    __shared__ bf16 sA[128 * 32];
    __shared__ bf16 sB[128 * 32];
    const int tid  = threadIdx.x;
    const int l15  = tid & 15;
    const int quad = (tid & 63) >> 4;
    const int wid  = tid >> 6;
    const int seg  = blockIdx.x >> 3;
    const int bn   = blockIdx.x & 7;
    const int bm   = blockIdx.y;
    const int wm   = (wid >> 1) * 64;
    const int wn   = (wid & 1) * 64;

    const bf16* W    = (seg == 0) ? Wq : (seg == 1) ? Wk : Wv;
    const float* bias = (seg == 0) ? bq : (seg == 1) ? bk : bv;

    const bf16* Ab = A + (size_t)bm * 128 * K;
    const bf16* Wb = W + (size_t)bn * 128 * K;

    f32x4 acc[4][4] = {};

    for (int k0 = 0; k0 < K; k0 += 32) {
        __syncthreads();
        #pragma unroll
        for (int it = 0; it < 2; ++it) {
            int c = it * 256 + tid;
            int row = c >> 2, c8 = c & 3;
            lds16(Ab + row * K + k0 + c8 * 8, (char*)sA + c * 16);
            lds16(Wb + row * K + k0 + c8 * 8, (char*)sB + c * 16);
        }
        __syncthreads();
        bf16x8 af[4], bfr[4];
        #pragma unroll
        for (int i = 0; i < 4; ++i)
            af[i] = *(const bf16x8*)&sA[(wm + i * 16 + l15) * 32 + quad * 8];
        #pragma unroll
        for (int i = 0; i < 4; ++i)
            bfr[i] = *(const bf16x8*)&sB[(wn + i * 16 + l15) * 32 + quad * 8];
        #pragma unroll
        for (int mi = 0; mi < 4; ++mi)
            #pragma unroll
            for (int ni = 0; ni < 4; ++ni)
                acc[mi][ni] = mfma16(af[mi], bfr[ni], acc[mi][ni]);
    }

    #pragma unroll
    for (int ni = 0; ni < 4; ++ni) {
        const int n  = bn * 128 + wn + ni * 16 + l15;   // 0..1023 within segment
        const float bv_ = bias[n];
        const int h = n >> 6;
        #pragma unroll
        for (int mi = 0; mi < 4; ++mi) {
            const int m0 = bm * 128 + wm + mi * 16 + quad * 4;
            if (seg == 2) {   // V transposed: [B,H,64,S]
                const int dv = n & 63;
                const int b = m0 >> 11, s = m0 & 2047;
                bf16x4 pack;
                #pragma unroll
                for (int r = 0; r < 4; ++r) pack[r] = (bf16)(acc[mi][ni][r] + bv_);
                *(bf16x4*)&Vw[(((size_t)(b * H_ + h) * HD + dv) << 11) + s] = pack;
            } else {          // Q,K: [B,H,S,64]
                bf16* C = (seg == 0) ? Qw : Kw;
                const int dk = n & 63;
                #pragma unroll
                for (int r = 0; r < 4; ++r) {
                    const int m = m0 + r, b = m >> 11, s = m & 2047;
                    C[(((size_t)(b * H_ + h) << 11) + s) * HD + dk] =
                        (bf16)(acc[mi][ni][r] + bv_);
                }
            }
        }
    }
}

// ---------------- final GEMM: out[M,N] fp32 = A @ Wo^T + bias ----------------
__global__ __launch_bounds__(256) void gemm_fin(const bf16* __restrict__ A,
                                                const bf16* __restrict__ W,
                                                const float* __restrict__ bias,
                                                float* __restrict__ C) {
    constexpr int N = 1024, K = 1024;
    __shared__ bf16 sA[128 * 32];
    __shared__ bf16 sB[128 * 32];
    const int tid  = threadIdx.x;
    const int l15  = tid & 15;
    const int quad = (tid & 63) >> 4;
    const int wid  = tid >> 6;
    const int bm   = blockIdx.x >> 3;
    const int bn   = blockIdx.x & 7;
    const int wm   = (wid >> 1) * 64;
    const int wn   = (wid & 1) * 64;

    const bf16* Ab = A + (size_t)bm * 128 * K;
    const bf16* Wb = W + (size_t)bn * 128 * K;

    f32x4 acc[4][4] = {};

    for (int k0 = 0; k0 < K; k0 += 32) {
        __syncthreads();
        #pragma unroll
        for (int it = 0; it < 2; ++it) {
            int c = it * 256 + tid;
            int row = c >> 2, c8 = c & 3;
            lds16(Ab + row * K + k0 + c8 * 8, (char*)sA + c * 16);
            lds16(Wb + row * K + k0 + c8 * 8, (char*)sB + c * 16);
        }
        __syncthreads();
        bf16x8 af[4], bfr[4];
        #pragma unroll
        for (int i = 0; i < 4; ++i)
            af[i] = *(const bf16x8*)&sA[(wm + i * 16 + l15) * 32 + quad * 8];
        #pragma unroll
        for (int i = 0; i < 4; ++i)
            bfr[i] = *(const bf16x8*)&sB[(wn + i * 16 + l15) * 32 + quad * 8];
        #pragma unroll
        for (int mi = 0; mi < 4; ++mi)
            #pragma unroll
            for (int ni = 0; ni < 4; ++ni)
                acc[mi][ni] = mfma16(af[mi], bfr[ni], acc[mi][ni]);
    }

    #pragma unroll
    for (int ni = 0; ni < 4; ++ni) {
        const int n  = bn * 128 + wn + ni * 16 + l15;
        const float bv = bias[n];
        #pragma unroll
        for (int mi = 0; mi < 4; ++mi) {
            const int m0 = bm * 128 + wm + mi * 16 + quad * 4;
            #pragma unroll
            for (int r = 0; r < 4; ++r)
                C[(size_t)(m0 + r) * N + n] = acc[mi][ni][r] + bv;
        }
    }
}

// ---------------- Flash attention ----------------
// 512 threads (8 waves), 128-row q tile, each wave owns 16 q rows.
// qt mapping pairs long+short blocks per CU; softmax in log2 domain.
// LDS: sK 16K + sV 16K + sPQ 32K (sQ staged into sPQ, dead after reg load).
__global__ __launch_bounds__(512, 4) void attn_k(const bf16* __restrict__ Q,
                                                 const bf16* __restrict__ K,
                                                 const bf16* __restrict__ Vt,
                                                 const float* __restrict__ pmask,
                                                 bf16* __restrict__ Aout) {
    __shared__ bf16 sK_[2 * 128 * 32];   // [kk][krow][32]
    __shared__ bf16 sV[4 * 64 * 32];     // [kc][dv][32]
    __shared__ bf16 sPQ[4 * 128 * 32];   // P: [kc][qrow][32]; also Q staging
    const int tid  = threadIdx.x;
    const int l15  = tid & 15;
    const int quad = (tid & 63) >> 4;
    const int wid  = tid >> 6;           // 0..7
    const int idx  = blockIdx.x >> 5;    // 0..15
    const int qt   = (idx < 8) ? (15 - idx) : (idx - 8);
    const int bh   = blockIdx.x & 31;
    const int b    = bh >> 4;
    const int h    = bh & 15;

    // stage Q into sPQ (plane layout [2][128][32]), load A-fragments, then reuse.
    const bf16* Qg = Q + ((size_t)bh * S_ + qt * 128) * HD;
    #pragma unroll
    for (int it = 0; it < 2; ++it) {
        int c = it * 512 + tid;
        int pl = c >> 9, row = (c >> 2) & 127, c8 = c & 3;
        lds16(Qg + row * HD + pl * 32 + c8 * 8, (char*)sPQ + c * 16);
    }
    __syncthreads();
    bf16x8 aq[2];
    #pragma unroll
    for (int kk = 0; kk < 2; ++kk)
        aq[kk] = *(const bf16x8*)&sPQ[(kk * 128 + wid * 16 + l15) * 32 + quad * 8];

    float m_i[4], l_i[4];
    f32x4 o[4] = {};
    #pragma unroll
    for (int r = 0; r < 4; ++r) { m_i[r] = NEG_BIG; l_i[r] = 0.f; }

    for (int kt = 0; kt <= qt; ++kt) {
        __syncthreads();                  // waves done with sK/sV/sPQ (incl. aq reads)
        const bf16* Kg = K  + ((size_t)bh * S_ + kt * 128) * HD;
        const bf16* Vg = Vt + (size_t)bh * HD * S_ + kt * 128;
        #pragma unroll
        for (int it = 0; it < 2; ++it) {
            int c = it * 512 + tid;
            { int pl = c >> 9, row = (c >> 2) & 127, c8 = c & 3;
              lds16(Kg + row * HD + pl * 32 + c8 * 8, (char*)sK_ + c * 16); }
            { int kc = c >> 8, dv = (c >> 2) & 63, c8 = c & 3;
              lds16(Vg + dv * S_ + kc * 32 + c8 * 8, (char*)sV + c * 16); }
        }
        __syncthreads();

        // S = Q K^T : 16 q rows x 128 keys per wave
        f32x4 s[8] = {};
        #pragma unroll
        for (int tc = 0; tc < 8; ++tc) {
            #pragma unroll
            for (int kk = 0; kk < 2; ++kk) {
                bf16x8 bk = *(const bf16x8*)
                    &sK_[(kk * 128 + tc * 16 + l15) * 32 + quad * 8];
                s[tc] = mfma16(aq[kk], bk, s[tc]);
            }
        }

        // scale (log2 domain) + padding + causal mask
        float pmadd[8];
        #pragma unroll
        for (int tc = 0; tc < 8; ++tc) {
            int kg = kt * 128 + tc * 16 + l15;
            pmadd[tc] = (pmask[b * S_ + kg] > 0.f) ? NEG_BIG : 0.f;
        }
        const bool diag = (kt == qt);
        #pragma unroll
        for (int tc = 0; tc < 8; ++tc)
            #pragma unroll
            for (int r = 0; r < 4; ++r) {
                float v = s[tc][r] * SCALE_LOG2E + pmadd[tc];
                if (diag) {
                    int kl = tc * 16 + l15;
                    int ql = wid * 16 + quad * 4 + r;
                    if (kl > ql) v = NEG_BIG;
                }
                s[tc][r] = v;
            }

        // online softmax (log2 domain), rows replicated across 16 lanes
        #pragma unroll
        for (int r = 0; r < 4; ++r) {
            float rm = s[0][r];
            #pragma unroll
            for (int tc = 1; tc < 8; ++tc) rm = fmaxf(rm, s[tc][r]);
            rm = fmaxf(rm, __shfl_xor(rm, 1, 16));
            rm = fmaxf(rm, __shfl_xor(rm, 2, 16));
            rm = fmaxf(rm, __shfl_xor(rm, 4, 16));
            rm = fmaxf(rm, __shfl_xor(rm, 8, 16));
            float mn    = fmaxf(m_i[r], rm);
            float alpha = exp2f(m_i[r] - mn);
            m_i[r]      = mn;
            float rs = 0.f;
            #pragma unroll
            for (int tc = 0; tc < 8; ++tc) {
                float p = exp2f(s[tc][r] - mn);
                s[tc][r] = p;
                rs += p;
            }
            rs += __shfl_xor(rs, 1, 16);
            rs += __shfl_xor(rs, 2, 16);
            rs += __shfl_xor(rs, 4, 16);
            rs += __shfl_xor(rs, 8, 16);
            l_i[r] = l_i[r] * alpha + rs;
            #pragma unroll
            for (int vc = 0; vc < 4; ++vc) o[vc][r] *= alpha;
        }

        // P: C-layout -> LDS (A-layout source for PV)
        #pragma unroll
        for (int tc = 0; tc < 8; ++tc)
            #pragma unroll
            for (int r = 0; r < 4; ++r) {
                int ql = wid * 16 + quad * 4 + r;
                int kl = tc * 16 + l15;
                sPQ[((kl >> 5) * 128 + ql) * 32 + (kl & 31)] = (bf16)s[tc][r];
            }
        __syncthreads();

        // O += P V
        #pragma unroll
        for (int kc = 0; kc < 4; ++kc) {
            bf16x8 ap = *(const bf16x8*)
                &sPQ[(kc * 128 + wid * 16 + l15) * 32 + quad * 8];
            #pragma unroll
            for (int vc = 0; vc < 4; ++vc) {
                bf16x8 bv = *(const bf16x8*)
                    &sV[(kc * 64 + vc * 16 + l15) * 32 + quad * 8];
                o[vc] = mfma16(ap, bv, o[vc]);
            }
        }
    }

    // epilogue: O/l -> att[B*S, H*64]
    #pragma unroll
    for (int r = 0; r < 4; ++r) {
        float inv = 1.f / l_i[r];
        int q = qt * 128 + wid * 16 + quad * 4 + r;
        size_t base = ((size_t)b * S_ + q) * D_ + h * HD;
        #pragma unroll
        for (int vc = 0; vc < 4; ++vc)
            Aout[base + vc * 16 + l15] = (bf16)(o[vc][r] * inv);
    }
}

extern "C" void kernel_launch(void* const* d_in, const int* in_sizes, int n_in,
                              void* d_out, int out_size, void* d_ws, size_t ws_size,
                              hipStream_t stream) {
    const float* X   = (const float*)d_in[0];
    const float* pm  = (const float*)d_in[1];
    const float* wq  = (const float*)d_in[2];
    const float* bq  = (const float*)d_in[3];
    const float* wk  = (const float*)d_in[4];
    const float* bk  = (const float*)d_in[5];
    const float* wv  = (const float*)d_in[6];
    const float* bvb = (const float*)d_in[7];
    const float* wo  = (const float*)d_in[8];
    const float* bo  = (const float*)d_in[9];
    float* out = (float*)d_out;

    char* ws = (char*)d_ws;
    bf16* Xb  = (bf16*)(ws);                  // 4M elems  8 MiB
    bf16* Wqb = (bf16*)(ws + (8u  << 20));    // 1M elems  2 MiB each
    bf16* Wkb = (bf16*)(ws + (10u << 20));
    bf16* Wvb = (bf16*)(ws + (12u << 20));
    bf16* Wob = (bf16*)(ws + (14u << 20));
    bf16* Qw  = (bf16*)(ws + (16u << 20));    // [B,H,S,64]  8 MiB
    bf16* Kw  = (bf16*)(ws + (24u << 20));    // [B,H,S,64]  8 MiB
    bf16* Vw  = (bf16*)(ws + (32u << 20));    // [B,H,64,S]  8 MiB
    bf16* Aw  = (bf16*)(ws + (40u << 20));    // [B*S, 1024] 8 MiB

    convert_k<<<dim3(8192), dim3(256), 0, stream>>>(X, wq, wk, wv, wo, Xb);
    gemm_qkv<<<dim3(24, 32), dim3(256), 0, stream>>>(Xb, Wqb, Wkb, Wvb,
                                                     bq, bk, bvb, Qw, Kw, Vw);
    attn_k<<<dim3(512), dim3(512), 0, stream>>>(Qw, Kw, Vw, pm, Aw);
    gemm_fin<<<dim3(256), dim3(256), 0, stream>>>(Aw, Wob, bo, out);
}